// Round 1
// baseline (5284.319 us; speedup 1.0000x reference)
//
#include <hip/hip_runtime.h>
#include <math.h>

#define MM     800
#define NN     8
#define KSEL   25
#define DIN    784
#define TSTEPS 256
#define MN     6400
#define NF4T   1600   // MN/4
#define STH    512    // scan threads
#define MAXK   4      // ceil(1600/512)

// ---------------- Kernel 1: A[t,m] = dot(W_a[m,:], x[t,:]) + b_a[m] ----------------
__global__ __launch_bounds__(256) void gemm_a_kernel(
    const float* __restrict__ x,    // (256,784)
    const float* __restrict__ Wa,   // (800,784)
    const float* __restrict__ ba,   // (800)
    float* __restrict__ A)          // (256,800)
{
  __shared__ float4 sx4[DIN / 4];   // 196 float4
  const int t = blockIdx.x;
  const int tid = threadIdx.x;
  if (tid < DIN / 4) sx4[tid] = ((const float4*)(x + t * DIN))[tid];
  __syncthreads();
  const int lane = tid & 63, wid = tid >> 6;
  for (int m = wid; m < MM; m += 4) {
    const float4* wrow = (const float4*)(Wa + m * DIN);
    float p = 0.f;
    for (int k4 = lane; k4 < DIN / 4; k4 += 64) {
      float4 w = wrow[k4];
      float4 xv = sx4[k4];
      p += w.x * xv.x + w.y * xv.y + w.z * xv.z + w.w * xv.w;
    }
    for (int off = 32; off; off >>= 1) p += __shfl_down(p, off, 64);
    if (lane == 0) A[t * MM + m] = p + ba[m];
  }
}

// ---------------- Kernel 2: WdT[g,d] = Wd[d,g]  (784x800 -> 800x784) ----------------
__global__ __launch_bounds__(256) void transpose_wd(
    const float* __restrict__ Wd, float* __restrict__ WdT)
{
  __shared__ float tile[32][33];
  const int bx = blockIdx.x * 32;  // g dim (800)
  const int by = blockIdx.y * 32;  // d dim (784)
  const int tx = threadIdx.x, ty = threadIdx.y;
  for (int r = ty; r < 32; r += 8) {
    int d = by + r, g = bx + tx;
    if (d < DIN && g < MM) tile[r][tx] = Wd[d * MM + g];
  }
  __syncthreads();
  for (int r = ty; r < 32; r += 8) {
    int g = bx + r, d = by + tx;
    if (g < MM && d < DIN) WdT[g * DIN + d] = tile[tx][r];
  }
}

// ---------------- Kernel 3: the sequential 256-step scan (single block) ----------------
__global__ __launch_bounds__(STH) void scan_kernel(
    const float* __restrict__ Wb,    // (6400,6400)
    const float* __restrict__ bb,    // (6400)
    const float* __restrict__ bd,    // (784)
    const float* __restrict__ Wd,    // (784,800) fallback
    const float* __restrict__ WdT,   // (800,784) or null
    const float* __restrict__ A,     // (256,800)
    float* __restrict__ out)         // 219904 floats
{
  __shared__ float4 s_sig4[NF4T];           // sigma, 25.6 KB
  __shared__ float  s_redmin[8], s_redbv[8];
  __shared__ int    s_redbi[8], s_redcnt[8];
  __shared__ float  s_sminS;
  __shared__ int    s_jstarS;

  const int tid = threadIdx.x;
  const int lane = tid & 63, wid = tid >> 6;
  const int nf4 = (tid < 64) ? MAXK : (MAXK - 1);   // 1600 = 3*512 + 64
  const float* sS = (const float*)s_sig4;

  // ---- one-time preloads into registers ----
  float4 bbv[MAXK];
  {
    const float4* bb4 = (const float4*)bb;
    for (int k = 0; k < nf4; k++) bbv[k] = bb4[tid + STH * k];
  }
  float bd0 = bd[tid];
  float bd1 = (tid < DIN - STH) ? bd[STH + tid] : 0.f;

  float4 av[MAXK];
  {
    const float* arow = A;  // t = 0
    for (int k = 0; k < nf4; k++) {
      int i = tid + STH * k;
      av[k] = *(const float4*)(arow + (i % 200) * 4);
    }
  }

  float colv[MAXK * 4];  // next-step W_b column (valid when act)
  int   jp = -1;
  float phiv = 0.f;
  int   act = 0;

  for (int t = 0; t < TSTEPS; t++) {
    // ---------- sigma + fused (min, argmax-excluding-jp) ----------
    float lmin = 3.4e38f;
    float bv = -3.4e38f;
    int   bi = MN;
    float4 sgk[MAXK];
    for (int k = 0; k < nf4; k++) {
      int i = tid + STH * k;
      float4 a4 = av[k];
      float4 s4;
      if (act) {  // match ref rounding: (a + col) + bb
        s4.x = (a4.x + colv[4 * k + 0]) + bbv[k].x;
        s4.y = (a4.y + colv[4 * k + 1]) + bbv[k].y;
        s4.z = (a4.z + colv[4 * k + 2]) + bbv[k].z;
        s4.w = (a4.w + colv[4 * k + 3]) + bbv[k].w;
      } else {
        s4.x = a4.x + bbv[k].x;
        s4.y = a4.y + bbv[k].y;
        s4.z = a4.z + bbv[k].z;
        s4.w = a4.w + bbv[k].w;
      }
      sgk[k] = s4;
      s_sig4[i] = s4;
      int j = 4 * i;
#define UPD(vv, jj)                                                        \
      {                                                                    \
        lmin = fminf(lmin, (vv));                                          \
        if ((jj) != jp && ((vv) > bv || ((vv) == bv && (jj) < bi))) {      \
          bv = (vv); bi = (jj);                                            \
        }                                                                  \
      }
      UPD(s4.x, j) UPD(s4.y, j + 1) UPD(s4.z, j + 2) UPD(s4.w, j + 3)
#undef UPD
    }
    // wave-level reduce: min and best(max, min-index ties)
    for (int off = 32; off; off >>= 1) {
      lmin = fminf(lmin, __shfl_down(lmin, off, 64));
      float ov = __shfl_down(bv, off, 64);
      int   oi = __shfl_down(bi, off, 64);
      if (ov > bv || (ov == bv && oi < bi)) { bv = ov; bi = oi; }
    }
    if (lane == 0) { s_redmin[wid] = lmin; s_redbv[wid] = bv; s_redbi[wid] = bi; }
    __syncthreads();  // B1
    if (tid == 0) {
      float mn = s_redmin[0];
      float v = s_redbv[0];
      int ji = s_redbi[0];
      for (int w = 1; w < 8; w++) {
        mn = fminf(mn, s_redmin[w]);
        float ov = s_redbv[w]; int oi = s_redbi[w];
        if (ov > v || (ov == v && oi < ji)) { v = ov; ji = oi; }
      }
      int js = ji;
      if (jp >= 0) {
        float piA = v - mn + 1.f;
        float pip = (sS[jp] - mn + 1.f) * (1.f - phiv);
        if (pip > piA || (pip == piA && jp < ji)) js = jp;
      }
      s_sminS = mn;
      s_jstarS = js;
    }
    __syncthreads();  // B2
    const float smin = s_sminS;
    const int jstar = s_jstarS;
    const int g = jstar >> 3;

    // ---------- prefetches (hide scattered-column latency behind lam phase) ----------
    float wd0, wd1;
    if (WdT) {
      const float* wrow = WdT + g * DIN;
      wd0 = wrow[tid];
      wd1 = (tid < DIN - STH) ? wrow[STH + tid] : 0.f;
    } else {
      wd0 = Wd[tid * MM + g];
      wd1 = (tid < DIN - STH) ? Wd[(STH + tid) * MM + g] : 0.f;
    }
    if (t + 1 < TSTEPS) {
      for (int k = 0; k < nf4; k++) {
        int j = 4 * (tid + STH * k);
        colv[4 * k + 0] = Wb[(j + 0) * MN + jstar];
        colv[4 * k + 1] = Wb[(j + 1) * MN + jstar];
        colv[4 * k + 2] = Wb[(j + 2) * MN + jstar];
        colv[4 * k + 3] = Wb[(j + 3) * MN + jstar];
      }
      const float* arow = A + (t + 1) * MM;
      for (int k = 0; k < nf4; k++) {
        int i = tid + STH * k;
        av[k] = *(const float4*)(arow + (i % 200) * 4);
      }
    }

    // ---------- top-K membership of group q = jstar % 800 ----------
    const int q = jstar % MM;
    float lamq;
    {
      float mq = -3.4e38f;
#pragma unroll
      for (int n = 0; n < 8; n++) {
        int j = q * 8 + n;
        float p = sS[j] - smin + 1.f;
        if (j == jp) p *= (1.f - phiv);
        mq = fmaxf(mq, p);
      }
      lamq = mq;
    }
    int cnt = 0;
    for (int k = 0; k < nf4; k++) {
      int i = tid + STH * k;
      float4 s4 = sgk[k];
      int j = 4 * i;
      float p0 = s4.x - smin + 1.f; if (j     == jp) p0 *= (1.f - phiv);
      float p1 = s4.y - smin + 1.f; if (j + 1 == jp) p1 *= (1.f - phiv);
      float p2 = s4.z - smin + 1.f; if (j + 2 == jp) p2 *= (1.f - phiv);
      float p3 = s4.w - smin + 1.f; if (j + 3 == jp) p3 *= (1.f - phiv);
      float pv = fmaxf(fmaxf(p0, p1), fmaxf(p2, p3));
      float ov = __shfl_xor(pv, 1, 64);   // partner half-group
      float lam = fmaxf(pv, ov);
      if ((i & 1) == 0) {                 // even half owns group g = i>>1
        int gg = i >> 1;
        if (lam > lamq || (lam == lamq && gg < q)) cnt++;
      }
    }
    for (int off = 32; off; off >>= 1) cnt += __shfl_down(cnt, off, 64);
    if (lane == 0) s_redcnt[wid] = cnt;
    float ts = tanhf(sS[jstar]);          // overlap transcendental with reduce
    __syncthreads();  // B3
    int total = 0;
#pragma unroll
    for (int w = 0; w < 8; w++) total += s_redcnt[w];
    const float ypos = (total < KSEL) ? fmaxf(ts, 0.f) : 0.f;

    // ---------- epilogue: preds row, final state outputs ----------
    float* pr = out + t * DIN;
    pr[tid] = wd0 * ypos + bd0;
    if (tid < DIN - STH) pr[STH + tid] = wd1 * ypos + bd1;

    if (t == TSTEPS - 1) {
      const float xbv = (ypos > 0.f) ? 1.f : 0.f;
      float* tail = out + TSTEPS * DIN;   // x_b | phi | psi
      for (int idx = tid; idx < 3 * MN; idx += STH) {
        float vwr = 0.f;
        if (idx == jstar)           vwr = xbv;
        else if (idx == MN + jstar)     vwr = ypos;
        else if (idx == 2 * MN + jstar) vwr = ypos;
        tail[idx] = vwr;
      }
    }

    // uniform state update
    jp = jstar;
    phiv = ypos;
    act = (ypos > 0.f) ? 1 : 0;
  }
}

extern "C" void kernel_launch(void* const* d_in, const int* in_sizes, int n_in,
                              void* d_out, int out_size, void* d_ws, size_t ws_size,
                              hipStream_t stream) {
  const float* x  = (const float*)d_in[0];
  const float* Wa = (const float*)d_in[1];
  const float* ba = (const float*)d_in[2];
  const float* Wb = (const float*)d_in[3];
  const float* bb = (const float*)d_in[4];
  const float* Wd = (const float*)d_in[5];
  const float* bd = (const float*)d_in[6];
  float* out = (float*)d_out;

  const size_t A_FLOATS = (size_t)TSTEPS * MM;      // 204800
  const size_t WDT_FLOATS = (size_t)MM * DIN;       // 627200

  float* Aptr;
  float* WdTptr = nullptr;
  if (ws_size >= (A_FLOATS + WDT_FLOATS) * sizeof(float)) {
    WdTptr = (float*)d_ws;
    Aptr = (float*)d_ws + WDT_FLOATS;
  } else if (ws_size >= A_FLOATS * sizeof(float)) {
    Aptr = (float*)d_ws;
  } else {
    // stash A in the preds region of d_out; scan overwrites it in a
    // provably non-overlapping order (preds[t] ends before A[t+1] begins).
    Aptr = out;
  }

  hipLaunchKernelGGL(gemm_a_kernel, dim3(TSTEPS), dim3(256), 0, stream,
                     x, Wa, ba, Aptr);
  if (WdTptr) {
    hipLaunchKernelGGL(transpose_wd, dim3(25, 25), dim3(32, 8), 0, stream,
                       Wd, WdTptr);
  }
  hipLaunchKernelGGL(scan_kernel, dim3(1), dim3(STH), 0, stream,
                     Wb, bb, bd, Wd, WdTptr, Aptr, out);
}

// Round 2
// 2725.356 us; speedup vs baseline: 1.9389x; 1.9389x over previous
//
#include <hip/hip_runtime.h>
#include <math.h>

#define MM     800
#define NN     8
#define KSEL   25
#define DIN    784
#define TSTEPS 256
#define MN     6400
#define NF4T   1600   // MN/4
#define STH    512    // scan threads
#define MAXK   4      // ceil(1600/512)

// ---------------- Kernel 1: A[t,m] = dot(W_a[m,:], x[t,:]) + b_a[m] ----------------
__global__ __launch_bounds__(256) void gemm_a_kernel(
    const float* __restrict__ x,    // (256,784)
    const float* __restrict__ Wa,   // (800,784)
    const float* __restrict__ ba,   // (800)
    float* __restrict__ A)          // (256,800)
{
  __shared__ float4 sx4[DIN / 4];   // 196 float4
  const int t = blockIdx.x;
  const int tid = threadIdx.x;
  if (tid < DIN / 4) sx4[tid] = ((const float4*)(x + t * DIN))[tid];
  __syncthreads();
  const int lane = tid & 63, wid = tid >> 6;
  for (int m = wid; m < MM; m += 4) {
    const float4* wrow = (const float4*)(Wa + m * DIN);
    float p = 0.f;
    for (int k4 = lane; k4 < DIN / 4; k4 += 64) {
      float4 w = wrow[k4];
      float4 xv = sx4[k4];
      p += w.x * xv.x + w.y * xv.y + w.z * xv.z + w.w * xv.w;
    }
    for (int off = 32; off; off >>= 1) p += __shfl_down(p, off, 64);
    if (lane == 0) A[t * MM + m] = p + ba[m];
  }
}

// ---------------- Kernel 2: WdT[g,d] = Wd[d,g]  (784x800 -> 800x784) ----------------
__global__ __launch_bounds__(256) void transpose_wd(
    const float* __restrict__ Wd, float* __restrict__ WdT)
{
  __shared__ float tile[32][33];
  const int bx = blockIdx.x * 32;  // g dim (800)
  const int by = blockIdx.y * 32;  // d dim (784)
  const int tx = threadIdx.x, ty = threadIdx.y;
  for (int r = ty; r < 32; r += 8) {
    int d = by + r, g = bx + tx;
    if (d < DIN && g < MM) tile[r][tx] = Wd[d * MM + g];
  }
  __syncthreads();
  for (int r = ty; r < 32; r += 8) {
    int g = bx + r, d = by + tx;
    if (g < MM && d < DIN) WdT[g * DIN + d] = tile[tx][r];
  }
}

// ---------------- Kernel 2b: WbT[c,r] = Wb[r,c]  (6400x6400) ----------------
__global__ __launch_bounds__(256) void transpose_wb(
    const float* __restrict__ Wb, float* __restrict__ WbT)
{
  __shared__ float tile[32][33];
  const int bx = blockIdx.x * 32;  // source col
  const int by = blockIdx.y * 32;  // source row
  const int tx = threadIdx.x, ty = threadIdx.y;  // 32x8
#pragma unroll
  for (int r = ty; r < 32; r += 8)
    tile[r][tx] = Wb[(size_t)(by + r) * MN + bx + tx];
  __syncthreads();
#pragma unroll
  for (int r = ty; r < 32; r += 8)
    WbT[(size_t)(bx + r) * MN + by + tx] = tile[tx][r];
}

// ---------------- Kernel 3: the sequential 256-step scan (single block) ----------------
__global__ __launch_bounds__(STH) void scan_kernel(
    const float* __restrict__ Wb,    // (6400,6400) fallback (column reads)
    const float* __restrict__ WbT,   // (6400,6400) transposed, or null
    const float* __restrict__ bb,    // (6400)
    const float* __restrict__ bd,    // (784)
    const float* __restrict__ Wd,    // (784,800) fallback
    const float* __restrict__ WdT,   // (800,784) or null
    const float* __restrict__ A,     // (256,800)
    float* __restrict__ out)         // 219904 floats
{
  __shared__ float4 s_sig4[NF4T];           // sigma, 25.6 KB
  __shared__ float  s_redmin[8], s_redbv[8];
  __shared__ int    s_redbi[8], s_redcnt[8];

  const int tid = threadIdx.x;
  const int lane = tid & 63, wid = tid >> 6;
  const int nf4 = (tid < 64) ? MAXK : (MAXK - 1);   // 1600 = 3*512 + 64
  const float* sS = (const float*)s_sig4;

  // ---- one-time preloads into registers ----
  float4 bbv[MAXK];
  {
    const float4* bb4 = (const float4*)bb;
    for (int k = 0; k < nf4; k++) bbv[k] = bb4[tid + STH * k];
  }
  float bd0 = bd[tid];
  float bd1 = (tid < DIN - STH) ? bd[STH + tid] : 0.f;

  float4 av[MAXK];
  {
    const float* arow = A;  // t = 0
    for (int k = 0; k < nf4; k++) {
      int i = tid + STH * k;
      av[k] = *(const float4*)(arow + (i % 200) * 4);
    }
  }

  float4 colv[MAXK];  // next-step W_b column chunk (valid when act)
  int   jp = -1;
  float phiv = 0.f;
  int   act = 0;

  for (int t = 0; t < TSTEPS; t++) {
    // ---------- sigma + fused (min, argmax-excluding-jp) ----------
    float lmin = 3.4e38f;
    float bv = -3.4e38f;
    int   bi = MN;
    float4 sgk[MAXK];
    for (int k = 0; k < nf4; k++) {
      int i = tid + STH * k;
      float4 a4 = av[k];
      float4 s4;
      if (act) {  // match ref rounding: (a + col) + bb
        s4.x = (a4.x + colv[k].x) + bbv[k].x;
        s4.y = (a4.y + colv[k].y) + bbv[k].y;
        s4.z = (a4.z + colv[k].z) + bbv[k].z;
        s4.w = (a4.w + colv[k].w) + bbv[k].w;
      } else {
        s4.x = a4.x + bbv[k].x;
        s4.y = a4.y + bbv[k].y;
        s4.z = a4.z + bbv[k].z;
        s4.w = a4.w + bbv[k].w;
      }
      sgk[k] = s4;
      s_sig4[i] = s4;
      int j = 4 * i;
#define UPD(vv, jj)                                                        \
      {                                                                    \
        lmin = fminf(lmin, (vv));                                          \
        if ((jj) != jp && ((vv) > bv || ((vv) == bv && (jj) < bi))) {      \
          bv = (vv); bi = (jj);                                            \
        }                                                                  \
      }
      UPD(s4.x, j) UPD(s4.y, j + 1) UPD(s4.z, j + 2) UPD(s4.w, j + 3)
#undef UPD
    }
    // wave-level reduce: min and best(max, min-index ties)
    for (int off = 32; off; off >>= 1) {
      lmin = fminf(lmin, __shfl_down(lmin, off, 64));
      float ov = __shfl_down(bv, off, 64);
      int   oi = __shfl_down(bi, off, 64);
      if (ov > bv || (ov == bv && oi < bi)) { bv = ov; bi = oi; }
    }
    if (lane == 0) { s_redmin[wid] = lmin; s_redbv[wid] = bv; s_redbi[wid] = bi; }
    __syncthreads();  // B1

    // ---------- redundant final reduce (all threads, identical result) ----------
    float smin, jsv;
    int jstar;
    {
      float mn = s_redmin[0];
      float v = s_redbv[0];
      int ji = s_redbi[0];
#pragma unroll
      for (int w = 1; w < 8; w++) {
        mn = fminf(mn, s_redmin[w]);
        float ov = s_redbv[w]; int oi = s_redbi[w];
        if (ov > v || (ov == v && oi < ji)) { v = ov; ji = oi; }
      }
      int js = ji;
      if (jp >= 0) {
        float piA = v - mn + 1.f;
        float pip = (sS[jp] - mn + 1.f) * (1.f - phiv);
        if (pip > piA || (pip == piA && jp < ji)) js = jp;
      }
      smin = mn;
      jstar = js;
      (void)jsv;
    }
    const int g = jstar >> 3;

    // ---------- prefetches (hide row-fetch latency behind lam phase) ----------
    float wd0, wd1;
    if (WdT) {
      const float* wrow = WdT + g * DIN;
      wd0 = wrow[tid];
      wd1 = (tid < DIN - STH) ? wrow[STH + tid] : 0.f;
    } else {
      wd0 = Wd[tid * MM + g];
      wd1 = (tid < DIN - STH) ? Wd[(STH + tid) * MM + g] : 0.f;
    }
    if (t + 1 < TSTEPS) {
      if (WbT) {
        const float4* wrow4 = (const float4*)(WbT + (size_t)jstar * MN);
        for (int k = 0; k < nf4; k++) colv[k] = wrow4[tid + STH * k];
      } else {
        for (int k = 0; k < nf4; k++) {
          int j = 4 * (tid + STH * k);
          colv[k].x = Wb[(size_t)(j + 0) * MN + jstar];
          colv[k].y = Wb[(size_t)(j + 1) * MN + jstar];
          colv[k].z = Wb[(size_t)(j + 2) * MN + jstar];
          colv[k].w = Wb[(size_t)(j + 3) * MN + jstar];
        }
      }
      const float* arow = A + (t + 1) * MM;
      for (int k = 0; k < nf4; k++) {
        int i = tid + STH * k;
        av[k] = *(const float4*)(arow + (i % 200) * 4);
      }
    }

    // ---------- top-K membership of group q = jstar % 800 ----------
    const int q = jstar % MM;
    float lamq;
    {
      float mq = -3.4e38f;
#pragma unroll
      for (int n = 0; n < 8; n++) {
        int j = q * 8 + n;
        float p = sS[j] - smin + 1.f;
        if (j == jp) p *= (1.f - phiv);
        mq = fmaxf(mq, p);
      }
      lamq = mq;
    }
    int cnt = 0;
    for (int k = 0; k < nf4; k++) {
      int i = tid + STH * k;
      float4 s4 = sgk[k];
      int j = 4 * i;
      float p0 = s4.x - smin + 1.f; if (j     == jp) p0 *= (1.f - phiv);
      float p1 = s4.y - smin + 1.f; if (j + 1 == jp) p1 *= (1.f - phiv);
      float p2 = s4.z - smin + 1.f; if (j + 2 == jp) p2 *= (1.f - phiv);
      float p3 = s4.w - smin + 1.f; if (j + 3 == jp) p3 *= (1.f - phiv);
      float pv = fmaxf(fmaxf(p0, p1), fmaxf(p2, p3));
      float ov = __shfl_xor(pv, 1, 64);   // partner half-group
      float lam = fmaxf(pv, ov);
      if ((i & 1) == 0) {                 // even half owns group gg = i>>1
        int gg = i >> 1;
        if (lam > lamq || (lam == lamq && gg < q)) cnt++;
      }
    }
    for (int off = 32; off; off >>= 1) cnt += __shfl_down(cnt, off, 64);
    if (lane == 0) s_redcnt[wid] = cnt;
    float ts = tanhf(sS[jstar]);          // overlap transcendental with reduce
    __syncthreads();  // B2

    int total = 0;
#pragma unroll
    for (int w = 0; w < 8; w++) total += s_redcnt[w];
    const float ypos = (total < KSEL) ? fmaxf(ts, 0.f) : 0.f;

    // ---------- epilogue: preds row, final state outputs ----------
    float* pr = out + t * DIN;
    pr[tid] = wd0 * ypos + bd0;
    if (tid < DIN - STH) pr[STH + tid] = wd1 * ypos + bd1;

    if (t == TSTEPS - 1) {
      const float xbv = (ypos > 0.f) ? 1.f : 0.f;
      float* tail = out + TSTEPS * DIN;   // x_b | phi | psi
      for (int idx = tid; idx < 3 * MN; idx += STH) {
        float vwr = 0.f;
        if (idx == jstar)               vwr = xbv;
        else if (idx == MN + jstar)     vwr = ypos;
        else if (idx == 2 * MN + jstar) vwr = ypos;
        tail[idx] = vwr;
      }
    }

    // uniform state update
    jp = jstar;
    phiv = ypos;
    act = (ypos > 0.f) ? 1 : 0;
  }
}

extern "C" void kernel_launch(void* const* d_in, const int* in_sizes, int n_in,
                              void* d_out, int out_size, void* d_ws, size_t ws_size,
                              hipStream_t stream) {
  const float* x  = (const float*)d_in[0];
  const float* Wa = (const float*)d_in[1];
  const float* ba = (const float*)d_in[2];
  const float* Wb = (const float*)d_in[3];
  const float* bb = (const float*)d_in[4];
  const float* Wd = (const float*)d_in[5];
  const float* bd = (const float*)d_in[6];
  float* out = (float*)d_out;

  const size_t A_FLOATS   = (size_t)TSTEPS * MM;   // 204800
  const size_t WDT_FLOATS = (size_t)MM * DIN;      // 627200
  const size_t WBT_FLOATS = (size_t)MN * MN;       // 40960000

  float* Aptr;
  float* WdTptr = nullptr;
  float* WbTptr = nullptr;
  if (ws_size >= (WBT_FLOATS + WDT_FLOATS + A_FLOATS) * sizeof(float)) {
    WbTptr = (float*)d_ws;
    WdTptr = WbTptr + WBT_FLOATS;
    Aptr   = WdTptr + WDT_FLOATS;
  } else if (ws_size >= (WDT_FLOATS + A_FLOATS) * sizeof(float)) {
    WdTptr = (float*)d_ws;
    Aptr   = WdTptr + WDT_FLOATS;
  } else if (ws_size >= A_FLOATS * sizeof(float)) {
    Aptr = (float*)d_ws;
  } else {
    // stash A in the preds region of d_out; scan overwrites it in a
    // provably non-overlapping order (preds[t] ends before A[t+1] begins).
    Aptr = out;
  }

  hipLaunchKernelGGL(gemm_a_kernel, dim3(TSTEPS), dim3(256), 0, stream,
                     x, Wa, ba, Aptr);
  if (WdTptr) {
    hipLaunchKernelGGL(transpose_wd, dim3(25, 25), dim3(32, 8), 0, stream,
                       Wd, WdTptr);
  }
  if (WbTptr) {
    hipLaunchKernelGGL(transpose_wb, dim3(200, 200), dim3(32, 8), 0, stream,
                       Wb, WbTptr);
  }
  hipLaunchKernelGGL(scan_kernel, dim3(1), dim3(STH), 0, stream,
                     Wb, WbTptr, bb, bd, Wd, WdTptr, Aptr, out);
}

// Round 4
// 2126.566 us; speedup vs baseline: 2.4849x; 1.2816x over previous
//
#include <hip/hip_runtime.h>
#include <math.h>

#define MM     800
#define NN     8
#define KSEL   25
#define DIN    784
#define TSTEPS 256
#define MN     6400
#define NF4T   1600   // MN/4
#define STH    1024   // scan threads: one reshape-group per thread (800 active)

// ---------------- Kernel 1: A[t,m] = dot(W_a[m,:], x[t,:]) + b_a[m] ----------------
__global__ __launch_bounds__(256) void gemm_a_kernel(
    const float* __restrict__ x,    // (256,784)
    const float* __restrict__ Wa,   // (800,784)
    const float* __restrict__ ba,   // (800)
    float* __restrict__ A)          // (256,800)
{
  __shared__ float4 sx4[DIN / 4];   // 196 float4
  const int t = blockIdx.x;
  const int tid = threadIdx.x;
  if (tid < DIN / 4) sx4[tid] = ((const float4*)(x + t * DIN))[tid];
  __syncthreads();
  const int lane = tid & 63, wid = tid >> 6;
  for (int m = wid; m < MM; m += 4) {
    const float4* wrow = (const float4*)(Wa + m * DIN);
    float p = 0.f;
    for (int k4 = lane; k4 < DIN / 4; k4 += 64) {
      float4 w = wrow[k4];
      float4 xv = sx4[k4];
      p += w.x * xv.x + w.y * xv.y + w.z * xv.z + w.w * xv.w;
    }
    for (int off = 32; off; off >>= 1) p += __shfl_down(p, off, 64);
    if (lane == 0) A[t * MM + m] = p + ba[m];
  }
}

// ---------------- Kernel 2: WdT[g,d] = Wd[d,g]  (784x800 -> 800x784) ----------------
__global__ __launch_bounds__(256) void transpose_wd(
    const float* __restrict__ Wd, float* __restrict__ WdT)
{
  __shared__ float tile[32][33];
  const int bx = blockIdx.x * 32;  // g dim (800)
  const int by = blockIdx.y * 32;  // d dim (784)
  const int tx = threadIdx.x, ty = threadIdx.y;
  for (int r = ty; r < 32; r += 8) {
    int d = by + r, g = bx + tx;
    if (d < DIN && g < MM) tile[r][tx] = Wd[d * MM + g];
  }
  __syncthreads();
  for (int r = ty; r < 32; r += 8) {
    int g = bx + r, d = by + tx;
    if (g < MM && d < DIN) WdT[g * DIN + d] = tile[tx][r];
  }
}

// ---------------- Kernel 2b: WbT[c,r] = Wb[r,c]  (6400x6400), 64x64 float4 tiles ----
__global__ __launch_bounds__(256) void transpose_wb64(
    const float* __restrict__ Wb, float* __restrict__ WbT)
{
  __shared__ float tile[64][65];
  const int bx = blockIdx.x * 64;   // src col base
  const int by = blockIdx.y * 64;   // src row base
  const int tx = threadIdx.x & 15;  // 16 float4 columns
  const int ty = threadIdx.x >> 4;  // 16 rows per pass
#pragma unroll
  for (int r = 0; r < 64; r += 16) {
    float4 v = *(const float4*)(Wb + (size_t)(by + r + ty) * MN + bx + 4 * tx);
    tile[r + ty][4 * tx + 0] = v.x;
    tile[r + ty][4 * tx + 1] = v.y;
    tile[r + ty][4 * tx + 2] = v.z;
    tile[r + ty][4 * tx + 3] = v.w;
  }
  __syncthreads();
#pragma unroll
  for (int r = 0; r < 64; r += 16) {
    float4 v;
    v.x = tile[4 * tx + 0][r + ty];
    v.y = tile[4 * tx + 1][r + ty];
    v.z = tile[4 * tx + 2][r + ty];
    v.w = tile[4 * tx + 3][r + ty];
    *(float4*)(WbT + (size_t)(bx + r + ty) * MN + by + 4 * tx) = v;
  }
}

// ---------------- Kernel 3: the sequential 256-step scan (single block) ----------------
__global__ __launch_bounds__(STH) void scan_kernel(
    const float* __restrict__ Wb,    // (6400,6400) fallback (column reads)
    const float* __restrict__ WbT,   // (6400,6400) transposed, or null
    const float* __restrict__ bb,    // (6400)
    const float* __restrict__ bd,    // (784)
    const float* __restrict__ Wd,    // (784,800) fallback
    const float* __restrict__ WdT,   // (800,784) or null
    const float* __restrict__ A,     // (256,800)
    float* __restrict__ out)         // 219904 floats
{
  __shared__ float4 s_sig4[NF4T];           // sigma, 25.6 KB
  __shared__ float  s_redmin[16], s_redbv[16];
  __shared__ int    s_redbi[16], s_redcnt[16];

  const int tid = threadIdx.x;
  const int lane = tid & 63, wid = tid >> 6;
  const bool own = (tid < MM);               // thread i owns group i (elements 8i..8i+7)
  const float* sS = (const float*)s_sig4;

  // A-row float4 offsets for elements (8i..8i+7) mod 800 — constant across t
  const int aofs = 2 * (tid % 100);

  // ---- one-time preloads into registers ----
  float4 bb0 = make_float4(0.f, 0.f, 0.f, 0.f), bb1 = bb0;
  if (own) {
    bb0 = ((const float4*)bb)[2 * tid];
    bb1 = ((const float4*)bb)[2 * tid + 1];
  }
  float bd0 = (tid < DIN) ? bd[tid] : 0.f;

  float4 av0 = make_float4(0.f, 0.f, 0.f, 0.f), av1 = av0;
  if (own) {
    av0 = ((const float4*)A)[aofs];
    av1 = ((const float4*)A)[aofs + 1];
  }

  float4 cv0 = make_float4(0.f, 0.f, 0.f, 0.f), cv1 = cv0;  // next-step W_b column chunk
  int   jp = -1;
  float phiv = 0.f;
  int   act = 0;

  for (int t = 0; t < TSTEPS; t++) {
    // ---------- sigma (8 elems, registers) + local min / argmax-excl-jp / group max ----------
    float s8[8];
    float lmin = 3.4e38f;
    float bv = -3.4e38f;
    int   bi = MN;
    float gmax = -3.4e38f;
    if (own) {
      float4 s40, s41;
      if (act) {  // match ref rounding: (a + col) + bb
        s40.x = (av0.x + cv0.x) + bb0.x;
        s40.y = (av0.y + cv0.y) + bb0.y;
        s40.z = (av0.z + cv0.z) + bb0.z;
        s40.w = (av0.w + cv0.w) + bb0.w;
        s41.x = (av1.x + cv1.x) + bb1.x;
        s41.y = (av1.y + cv1.y) + bb1.y;
        s41.z = (av1.z + cv1.z) + bb1.z;
        s41.w = (av1.w + cv1.w) + bb1.w;
      } else {
        s40.x = av0.x + bb0.x;
        s40.y = av0.y + bb0.y;
        s40.z = av0.z + bb0.z;
        s40.w = av0.w + bb0.w;
        s41.x = av1.x + bb1.x;
        s41.y = av1.y + bb1.y;
        s41.z = av1.z + bb1.z;
        s41.w = av1.w + bb1.w;
      }
      s_sig4[2 * tid] = s40;
      s_sig4[2 * tid + 1] = s41;
      s8[0] = s40.x; s8[1] = s40.y; s8[2] = s40.z; s8[3] = s40.w;
      s8[4] = s41.x; s8[5] = s41.y; s8[6] = s41.z; s8[7] = s41.w;
      const int jb = 8 * tid;
#pragma unroll
      for (int k = 0; k < 8; k++) {
        float v = s8[k];
        lmin = fminf(lmin, v);
        gmax = fmaxf(gmax, v);
        int j = jb + k;
        if (j != jp && (v > bv || (v == bv && j < bi))) { bv = v; bi = j; }
      }
    }

    // ---------- wave reduce: min and best(max, min-index ties) ----------
    for (int off = 32; off; off >>= 1) {
      lmin = fminf(lmin, __shfl_down(lmin, off, 64));
      float ov = __shfl_down(bv, off, 64);
      int   oi = __shfl_down(bi, off, 64);
      if (ov > bv || (ov == bv && oi < bi)) { bv = ov; bi = oi; }
    }
    if (lane == 0) { s_redmin[wid] = lmin; s_redbv[wid] = bv; s_redbi[wid] = bi; }
    __syncthreads();  // B1

    // ---------- redundant final reduce (all threads, identical result) ----------
    float smin;
    int jstar;
    {
      float mn = s_redmin[0];
      float v = s_redbv[0];
      int ji = s_redbi[0];
#pragma unroll
      for (int w = 1; w < 16; w++) {
        mn = fminf(mn, s_redmin[w]);
        float ov = s_redbv[w]; int oi = s_redbi[w];
        if (ov > v || (ov == v && oi < ji)) { v = ov; ji = oi; }
      }
      int js = ji;
      if (jp >= 0) {
        float piA = v - mn + 1.f;
        float pip = (sS[jp] - mn + 1.f) * (1.f - phiv);
        if (pip > piA || (pip == piA && jp < ji)) js = jp;
      }
      smin = mn;
      jstar = js;
    }
    const int g = jstar >> 3;
    const int q = jstar % MM;

    // ---------- prefetches (all after jstar; independent loads overlap) ----------
    if (t + 1 < TSTEPS && own) {
      if (WbT) {
        const float4* w4 = (const float4*)(WbT + (size_t)jstar * MN);
        cv0 = w4[2 * tid];
        cv1 = w4[2 * tid + 1];
      } else {
        const int jb = 8 * tid;
        cv0.x = Wb[(size_t)(jb + 0) * MN + jstar];
        cv0.y = Wb[(size_t)(jb + 1) * MN + jstar];
        cv0.z = Wb[(size_t)(jb + 2) * MN + jstar];
        cv0.w = Wb[(size_t)(jb + 3) * MN + jstar];
        cv1.x = Wb[(size_t)(jb + 4) * MN + jstar];
        cv1.y = Wb[(size_t)(jb + 5) * MN + jstar];
        cv1.z = Wb[(size_t)(jb + 6) * MN + jstar];
        cv1.w = Wb[(size_t)(jb + 7) * MN + jstar];
      }
      const float4* arow4 = (const float4*)(A + (size_t)(t + 1) * MM);
      av0 = arow4[aofs];
      av1 = arow4[aofs + 1];
    }
    float wd0v = 0.f;
    if (tid < DIN) wd0v = WdT ? WdT[g * DIN + tid] : Wd[tid * MM + g];

    // ---------- lam_q (redundant, LDS broadcasts) ----------
    float lamq = -3.4e38f;
#pragma unroll
    for (int n = 0; n < 8; n++) {
      int j = q * 8 + n;
      float p = sS[j] - smin + 1.f;
      if (j == jp) p *= (1.f - phiv);
      lamq = fmaxf(lamq, p);
    }

    // ---------- own-group lam vs lam_q: 1 compare; ballot count ----------
    int cnt = 0;
    if (own) {
      float lam;
      if (jp >= 0 && (jp >> 3) == tid) {
        // group contains jp: per-element with fixup, same op order as lamq loop
        lam = -3.4e38f;
#pragma unroll
        for (int n = 0; n < 8; n++) {
          float p = s8[n] - smin + 1.f;
          if (8 * tid + n == jp) p *= (1.f - phiv);
          lam = fmaxf(lam, p);
        }
      } else {
        lam = gmax - smin + 1.f;  // exact: weakly-monotone map commutes with max
      }
      if (lam > lamq || (lam == lamq && tid < q)) cnt = 1;
    }
    unsigned long long ball = __ballot(cnt != 0);
    if (lane == 0) s_redcnt[wid] = __popcll(ball);
    float ts = tanhf(sS[jstar]);          // overlap transcendental with reduce
    __syncthreads();  // B2

    int total = 0;
#pragma unroll
    for (int w = 0; w < 16; w++) total += s_redcnt[w];
    const float ypos = (total < KSEL) ? fmaxf(ts, 0.f) : 0.f;

    // ---------- epilogue: preds row, final state outputs ----------
    if (tid < DIN) out[t * DIN + tid] = wd0v * ypos + bd0;

    if (t == TSTEPS - 1) {
      const float xbv = (ypos > 0.f) ? 1.f : 0.f;
      float* tail = out + TSTEPS * DIN;   // x_b | phi | psi
      for (int idx = tid; idx < 3 * MN; idx += STH) {
        float vwr = 0.f;
        if (idx == jstar)               vwr = xbv;
        else if (idx == MN + jstar)     vwr = ypos;
        else if (idx == 2 * MN + jstar) vwr = ypos;
        tail[idx] = vwr;
      }
    }

    // uniform state update
    jp = jstar;
    phiv = ypos;
    act = (ypos > 0.f) ? 1 : 0;
  }
}

extern "C" void kernel_launch(void* const* d_in, const int* in_sizes, int n_in,
                              void* d_out, int out_size, void* d_ws, size_t ws_size,
                              hipStream_t stream) {
  const float* x  = (const float*)d_in[0];
  const float* Wa = (const float*)d_in[1];
  const float* ba = (const float*)d_in[2];
  const float* Wb = (const float*)d_in[3];
  const float* bb = (const float*)d_in[4];
  const float* Wd = (const float*)d_in[5];
  const float* bd = (const float*)d_in[6];
  float* out = (float*)d_out;

  const size_t A_FLOATS   = (size_t)TSTEPS * MM;   // 204800
  const size_t WDT_FLOATS = (size_t)MM * DIN;      // 627200
  const size_t WBT_FLOATS = (size_t)MN * MN;       // 40960000

  float* Aptr;
  float* WdTptr = nullptr;
  float* WbTptr = nullptr;
  if (ws_size >= (WBT_FLOATS + WDT_FLOATS + A_FLOATS) * sizeof(float)) {
    WbTptr = (float*)d_ws;
    WdTptr = WbTptr + WBT_FLOATS;
    Aptr   = WdTptr + WDT_FLOATS;
  } else if (ws_size >= (WDT_FLOATS + A_FLOATS) * sizeof(float)) {
    WdTptr = (float*)d_ws;
    Aptr   = WdTptr + WDT_FLOATS;
  } else if (ws_size >= A_FLOATS * sizeof(float)) {
    Aptr = (float*)d_ws;
  } else {
    // stash A in the preds region of d_out; scan reads A[t+1] before preds[t]
    // is written and 800(t+1) > 784t+784 for all t, so regions never collide.
    Aptr = out;
  }

  hipLaunchKernelGGL(gemm_a_kernel, dim3(TSTEPS), dim3(256), 0, stream,
                     x, Wa, ba, Aptr);
  if (WdTptr) {
    hipLaunchKernelGGL(transpose_wd, dim3(25, 25), dim3(32, 8), 0, stream,
                       Wd, WdTptr);
  }
  if (WbTptr) {
    hipLaunchKernelGGL(transpose_wb64, dim3(100, 100), dim3(256), 0, stream,
                       Wb, WbTptr);
  }
  hipLaunchKernelGGL(scan_kernel, dim3(1), dim3(STH), 0, stream,
                     Wb, WbTptr, bb, bd, Wd, WdTptr, Aptr, out);
}

// Round 5
// 1956.648 us; speedup vs baseline: 2.7007x; 1.0868x over previous
//
#include <hip/hip_runtime.h>
#include <math.h>

#define MM     800
#define NN     8
#define KSEL   25
#define DIN    784
#define TSTEPS 256
#define MN     6400
#define SCTH   256    // scan threads: 4 waves; thread owns groups tid, tid+256, tid+512 (+tid+768 if tid<32)

// ---------------- Kernel 1: A[t,m] = dot(W_a[m,:], x[t,:]) + b_a[m] ----------------
__global__ __launch_bounds__(256) void gemm_a_kernel(
    const float* __restrict__ x,    // (256,784)
    const float* __restrict__ Wa,   // (800,784)
    const float* __restrict__ ba,   // (800)
    float* __restrict__ A)          // (256,800)
{
  __shared__ float4 sx4[DIN / 4];   // 196 float4
  const int t = blockIdx.x;
  const int tid = threadIdx.x;
  if (tid < DIN / 4) sx4[tid] = ((const float4*)(x + t * DIN))[tid];
  __syncthreads();
  const int lane = tid & 63, wid = tid >> 6;
  for (int m = wid; m < MM; m += 4) {
    const float4* wrow = (const float4*)(Wa + m * DIN);
    float p = 0.f;
    for (int k4 = lane; k4 < DIN / 4; k4 += 64) {
      float4 w = wrow[k4];
      float4 xv = sx4[k4];
      p += w.x * xv.x + w.y * xv.y + w.z * xv.z + w.w * xv.w;
    }
    for (int off = 32; off; off >>= 1) p += __shfl_down(p, off, 64);
    if (lane == 0) A[t * MM + m] = p + ba[m];
  }
}

// ---------------- Kernel 2: WdT[g,d] = Wd[d,g]  (784x800 -> 800x784) ----------------
__global__ __launch_bounds__(256) void transpose_wd(
    const float* __restrict__ Wd, float* __restrict__ WdT)
{
  __shared__ float tile[32][33];
  const int bx = blockIdx.x * 32;  // g dim (800)
  const int by = blockIdx.y * 32;  // d dim (784)
  const int tx = threadIdx.x, ty = threadIdx.y;
  for (int r = ty; r < 32; r += 8) {
    int d = by + r, g = bx + tx;
    if (d < DIN && g < MM) tile[r][tx] = Wd[d * MM + g];
  }
  __syncthreads();
  for (int r = ty; r < 32; r += 8) {
    int g = bx + r, d = by + tx;
    if (g < MM && d < DIN) WdT[g * DIN + d] = tile[tx][r];
  }
}

// ---------------- Kernel 2b: WbT[c,r] = Wb[r,c]  (6400x6400), 64x64 float4 tiles ----
__global__ __launch_bounds__(256) void transpose_wb64(
    const float* __restrict__ Wb, float* __restrict__ WbT)
{
  __shared__ float tile[64][65];
  const int bx = blockIdx.x * 64;   // src col base
  const int by = blockIdx.y * 64;   // src row base
  const int tx = threadIdx.x & 15;  // 16 float4 columns
  const int ty = threadIdx.x >> 4;  // 16 rows per pass
#pragma unroll
  for (int r = 0; r < 64; r += 16) {
    float4 v = *(const float4*)(Wb + (size_t)(by + r + ty) * MN + bx + 4 * tx);
    tile[r + ty][4 * tx + 0] = v.x;
    tile[r + ty][4 * tx + 1] = v.y;
    tile[r + ty][4 * tx + 2] = v.z;
    tile[r + ty][4 * tx + 3] = v.w;
  }
  __syncthreads();
#pragma unroll
  for (int r = 0; r < 64; r += 16) {
    float4 v;
    v.x = tile[4 * tx + 0][r + ty];
    v.y = tile[4 * tx + 1][r + ty];
    v.z = tile[4 * tx + 2][r + ty];
    v.w = tile[4 * tx + 3][r + ty];
    *(float4*)(WbT + (size_t)(bx + r + ty) * MN + by + 4 * tx) = v;
  }
}

// ---------------- Kernel 3: the sequential 256-step scan (single block, 4 waves) ----
__global__ __launch_bounds__(SCTH, 1) void scan_kernel(
    const float* __restrict__ Wb,    // (6400,6400) fallback (column reads)
    const float* __restrict__ WbT,   // (6400,6400) transposed, or null
    const float* __restrict__ bb,    // (6400)
    const float* __restrict__ bd,    // (784)
    const float* __restrict__ Wd,    // (784,800) fallback
    const float* __restrict__ WdT,   // (800,784) or null
    const float* __restrict__ A,     // (256,800)
    float* __restrict__ out)         // 219904 floats
{
  // Double-buffered by step parity: one __syncthreads per step; a wave can run
  // at most one step ahead, so writes(t+1) land in buffer 1-p while stragglers
  // still read buffer p.
  __shared__ float s_sig[2][MN];    // 51.2 KB
  __shared__ float s_lam[2][MM];    // 6.4 KB  (raw per-group max of sigma)
  __shared__ float s_rmin[2][4];
  __shared__ float s_rbv[2][4];
  __shared__ int   s_rbi[2][4];

  const int tid = threadIdx.x;
  const int lane = tid & 63, wid = tid >> 6;
  const bool has4 = (tid < 32);     // 800 = 3*256 + 32

  int aoff[4];                      // float4 offset of group g's A slice: 8g mod 800
  float4 bbv[4][2], av[4][2], cv[4][2];
#pragma unroll
  for (int s = 0; s < 4; s++) {
    const int g = tid + SCTH * s;
    const bool v = (s < 3) || has4;
    aoff[s] = 2 * (g % 100);
    if (v) {
      bbv[s][0] = ((const float4*)bb)[2 * g];
      bbv[s][1] = ((const float4*)bb)[2 * g + 1];
      av[s][0] = ((const float4*)A)[aoff[s]];       // t = 0 row
      av[s][1] = ((const float4*)A)[aoff[s] + 1];
    } else {
      bbv[s][0] = bbv[s][1] = make_float4(0.f, 0.f, 0.f, 0.f);
      av[s][0] = av[s][1] = make_float4(0.f, 0.f, 0.f, 0.f);
      cv[s][0] = cv[s][1] = make_float4(0.f, 0.f, 0.f, 0.f);
    }
  }
  float4 bd4 = make_float4(0.f, 0.f, 0.f, 0.f);
  if (tid < DIN / 4) bd4 = ((const float4*)bd)[tid];

  int jp = -1;
  float phiv = 0.f;
  int act = 0;

  for (int t = 0; t < TSTEPS; t++) {
    const int p = t & 1;

    // ---------- sigma (registers) + local min / argmax-excl-jp / group max ----------
    float lmin = 3.4e38f, bv = -3.4e38f;
    int bi = MN;
#pragma unroll
    for (int s = 0; s < 4; s++) {
      const bool v = (s < 3) || has4;
      if (v) {
        const int g = tid + SCTH * s;
        float4 x0, x1;
        if (act) {  // match ref rounding: (a + col) + bb
          x0.x = (av[s][0].x + cv[s][0].x) + bbv[s][0].x;
          x0.y = (av[s][0].y + cv[s][0].y) + bbv[s][0].y;
          x0.z = (av[s][0].z + cv[s][0].z) + bbv[s][0].z;
          x0.w = (av[s][0].w + cv[s][0].w) + bbv[s][0].w;
          x1.x = (av[s][1].x + cv[s][1].x) + bbv[s][1].x;
          x1.y = (av[s][1].y + cv[s][1].y) + bbv[s][1].y;
          x1.z = (av[s][1].z + cv[s][1].z) + bbv[s][1].z;
          x1.w = (av[s][1].w + cv[s][1].w) + bbv[s][1].w;
        } else {
          x0.x = av[s][0].x + bbv[s][0].x;
          x0.y = av[s][0].y + bbv[s][0].y;
          x0.z = av[s][0].z + bbv[s][0].z;
          x0.w = av[s][0].w + bbv[s][0].w;
          x1.x = av[s][1].x + bbv[s][1].x;
          x1.y = av[s][1].y + bbv[s][1].y;
          x1.z = av[s][1].z + bbv[s][1].z;
          x1.w = av[s][1].w + bbv[s][1].w;
        }
        *(float4*)&s_sig[p][8 * g]     = x0;
        *(float4*)&s_sig[p][8 * g + 4] = x1;
        float e[8] = {x0.x, x0.y, x0.z, x0.w, x1.x, x1.y, x1.z, x1.w};
        const int kx = ((jp >> 3) == g) ? (jp & 7) : 8;  // excluded element, 8 = none
        float gm = -3.4e38f;
#pragma unroll
        for (int k = 0; k < 8; k++) {
          const float vv = e[k];
          lmin = fminf(lmin, vv);
          gm = fmaxf(gm, vv);
          const int j = 8 * g + k;
          if (k != kx && (vv > bv || (vv == bv && j < bi))) { bv = vv; bi = j; }
        }
        s_lam[p][g] = gm;
      }
    }

    // ---------- wave reduce: min and best(max, min-index ties) ----------
#pragma unroll
    for (int off = 32; off; off >>= 1) {
      lmin = fminf(lmin, __shfl_down(lmin, off, 64));
      float ov = __shfl_down(bv, off, 64);
      int oi = __shfl_down(bi, off, 64);
      if (ov > bv || (ov == bv && oi < bi)) { bv = ov; bi = oi; }
    }
    if (lane == 0) { s_rmin[p][wid] = lmin; s_rbv[p][wid] = bv; s_rbi[p][wid] = bi; }
    __syncthreads();  // the ONE barrier per step

    // ---------- redundant final reduce over 4 partials (all threads, identical) -----
    float smin;
    int jstar;
    {
      float mn = s_rmin[p][0];
      float v = s_rbv[p][0];
      int ji = s_rbi[p][0];
#pragma unroll
      for (int w = 1; w < 4; w++) {
        mn = fminf(mn, s_rmin[p][w]);
        float ov = s_rbv[p][w];
        int oi = s_rbi[p][w];
        if (ov > v || (ov == v && oi < ji)) { v = ov; ji = oi; }
      }
      int js = ji;
      if (jp >= 0) {
        float piA = v - mn + 1.f;
        float pip = (s_sig[p][jp] - mn + 1.f) * (1.f - phiv);
        if (pip > piA || (pip == piA && jp < ji)) js = jp;
      }
      smin = mn;
      jstar = js;
    }
    const int gw = jstar >> 3;   // reshape row -> Wd column
    const int q = jstar % MM;    // lam group gating y[jstar]

    // ---------- prefetch next-step data (post-jstar; crosses no barrier) ----------
    if (t + 1 < TSTEPS) {
      if (WbT) {
        const float4* w4 = (const float4*)(WbT + (size_t)jstar * MN);
#pragma unroll
        for (int s = 0; s < 4; s++) {
          const bool v = (s < 3) || has4;
          const int g = tid + SCTH * s;
          if (v) { cv[s][0] = w4[2 * g]; cv[s][1] = w4[2 * g + 1]; }
        }
      } else {
#pragma unroll
        for (int s = 0; s < 4; s++) {
          const bool v = (s < 3) || has4;
          const int g = tid + SCTH * s;
          if (v) {
            const int jb = 8 * g;
            cv[s][0].x = Wb[(size_t)(jb + 0) * MN + jstar];
            cv[s][0].y = Wb[(size_t)(jb + 1) * MN + jstar];
            cv[s][0].z = Wb[(size_t)(jb + 2) * MN + jstar];
            cv[s][0].w = Wb[(size_t)(jb + 3) * MN + jstar];
            cv[s][1].x = Wb[(size_t)(jb + 4) * MN + jstar];
            cv[s][1].y = Wb[(size_t)(jb + 5) * MN + jstar];
            cv[s][1].z = Wb[(size_t)(jb + 6) * MN + jstar];
            cv[s][1].w = Wb[(size_t)(jb + 7) * MN + jstar];
          }
        }
      }
      const float4* ar = (const float4*)(A + (size_t)(t + 1) * MM);
#pragma unroll
      for (int s = 0; s < 4; s++) {
        const bool v = (s < 3) || has4;
        if (v) { av[s][0] = ar[aoff[s]]; av[s][1] = ar[aoff[s] + 1]; }
      }
    }
    float4 wd4 = make_float4(0.f, 0.f, 0.f, 0.f);
    if (tid < DIN / 4) {
      if (WdT) {
        wd4 = ((const float4*)(WdT + (size_t)gw * DIN))[tid];
      } else {
        wd4.x = Wd[(size_t)(4 * tid + 0) * MM + gw];
        wd4.y = Wd[(size_t)(4 * tid + 1) * MM + gw];
        wd4.z = Wd[(size_t)(4 * tid + 2) * MM + gw];
        wd4.w = Wd[(size_t)(4 * tid + 3) * MM + gw];
      }
    }

    // ---------- pi-space lam of jp's group (the only group the affine map misses) ---
    const int jpg = (jp >= 0) ? (jp >> 3) : -1;
    float lamfix = -3.4e38f;
    if (jp >= 0) {
      float4 f0 = *(const float4*)&s_sig[p][8 * jpg];
      float4 f1 = *(const float4*)&s_sig[p][8 * jpg + 4];
      float e[8] = {f0.x, f0.y, f0.z, f0.w, f1.x, f1.y, f1.z, f1.w};
#pragma unroll
      for (int k = 0; k < 8; k++) {
        float pv = e[k] - smin + 1.f;
        if (8 * jpg + k == jp) pv *= (1.f - phiv);
        lamfix = fmaxf(lamfix, pv);
      }
    }
    const float keyq = (q == jpg) ? lamfix : (s_lam[p][q] - smin + 1.f);

    // ---------- rank of group q among 800 lams: per-wave redundant ballot count -----
    int total = 0;
    const float4* lam4 = (const float4*)&s_lam[p][0];  // 200 float4
#pragma unroll
    for (int i = 0; i < 4; i++) {
      const int i4 = lane + 64 * i;
      const bool vld = (i4 < MM / 4);
      float4 lv = make_float4(-3.4e38f, -3.4e38f, -3.4e38f, -3.4e38f);
      if (vld) lv = lam4[i4];
      const int gb = 4 * i4;
      {
        float key = (gb + 0 == jpg) ? lamfix : (lv.x - smin + 1.f);
        total += __popcll(__ballot(vld && (key > keyq || (key == keyq && gb + 0 < q))));
      }
      {
        float key = (gb + 1 == jpg) ? lamfix : (lv.y - smin + 1.f);
        total += __popcll(__ballot(vld && (key > keyq || (key == keyq && gb + 1 < q))));
      }
      {
        float key = (gb + 2 == jpg) ? lamfix : (lv.z - smin + 1.f);
        total += __popcll(__ballot(vld && (key > keyq || (key == keyq && gb + 2 < q))));
      }
      {
        float key = (gb + 3 == jpg) ? lamfix : (lv.w - smin + 1.f);
        total += __popcll(__ballot(vld && (key > keyq || (key == keyq && gb + 3 < q))));
      }
    }
    const float ts = tanhf(s_sig[p][jstar]);
    const float ypos = (total < KSEL) ? fmaxf(ts, 0.f) : 0.f;

    // ---------- epilogue: preds row, final state outputs ----------
    if (tid < DIN / 4) {
      float4 pr;
      pr.x = wd4.x * ypos + bd4.x;
      pr.y = wd4.y * ypos + bd4.y;
      pr.z = wd4.z * ypos + bd4.z;
      pr.w = wd4.w * ypos + bd4.w;
      *(float4*)(out + (size_t)t * DIN + 4 * tid) = pr;
    }
    if (t == TSTEPS - 1) {
      const float xbv = (ypos > 0.f) ? 1.f : 0.f;
      float* tail = out + TSTEPS * DIN;   // x_b | phi | psi
      for (int idx = tid; idx < 3 * MN; idx += SCTH) {
        float vwr = 0.f;
        if (idx == jstar)               vwr = xbv;
        else if (idx == MN + jstar)     vwr = ypos;
        else if (idx == 2 * MN + jstar) vwr = ypos;
        tail[idx] = vwr;
      }
    }

    // uniform state update
    jp = jstar;
    phiv = ypos;
    act = (ypos > 0.f) ? 1 : 0;
  }
}

extern "C" void kernel_launch(void* const* d_in, const int* in_sizes, int n_in,
                              void* d_out, int out_size, void* d_ws, size_t ws_size,
                              hipStream_t stream) {
  const float* x  = (const float*)d_in[0];
  const float* Wa = (const float*)d_in[1];
  const float* ba = (const float*)d_in[2];
  const float* Wb = (const float*)d_in[3];
  const float* bb = (const float*)d_in[4];
  const float* Wd = (const float*)d_in[5];
  const float* bd = (const float*)d_in[6];
  float* out = (float*)d_out;

  const size_t A_FLOATS   = (size_t)TSTEPS * MM;   // 204800
  const size_t WDT_FLOATS = (size_t)MM * DIN;      // 627200
  const size_t WBT_FLOATS = (size_t)MN * MN;       // 40960000

  float* Aptr;
  float* WdTptr = nullptr;
  float* WbTptr = nullptr;
  if (ws_size >= (WBT_FLOATS + WDT_FLOATS + A_FLOATS) * sizeof(float)) {
    WbTptr = (float*)d_ws;
    WdTptr = WbTptr + WBT_FLOATS;
    Aptr   = WdTptr + WDT_FLOATS;
  } else if (ws_size >= (WDT_FLOATS + A_FLOATS) * sizeof(float)) {
    WdTptr = (float*)d_ws;
    Aptr   = WdTptr + WDT_FLOATS;
  } else if (ws_size >= A_FLOATS * sizeof(float)) {
    Aptr = (float*)d_ws;
  } else {
    // stash A in the preds region of d_out; scan reads A[t+1] before writing
    // preds[t] and 800(t+1) >= 784t+784 for all t, so regions never collide.
    Aptr = out;
  }

  hipLaunchKernelGGL(gemm_a_kernel, dim3(TSTEPS), dim3(256), 0, stream,
                     x, Wa, ba, Aptr);
  if (WdTptr) {
    hipLaunchKernelGGL(transpose_wd, dim3(25, 25), dim3(32, 8), 0, stream,
                       Wd, WdTptr);
  }
  if (WbTptr) {
    hipLaunchKernelGGL(transpose_wb64, dim3(100, 100), dim3(256), 0, stream,
                       Wb, WbTptr);
  }
  hipLaunchKernelGGL(scan_kernel, dim3(1), dim3(SCTH), 0, stream,
                     Wb, WbTptr, bb, bd, Wd, WdTptr, Aptr, out);
}